// Round 2
// baseline (104.390 us; speedup 1.0000x reference)
//
#include <hip/hip_runtime.h>

#define NNODE 62
#define FIN 5
#define HID 400
#define NTRIL 1953
#define MST 63          // padded row stride of M (62+1, odd => conflict-free column reads)

typedef __attribute__((ext_vector_type(8))) short bf16x8;
typedef __attribute__((ext_vector_type(4))) float f32x4;

// float -> bf16 bits, round-to-nearest-even
static __device__ __forceinline__ short f2bf(float x) {
    unsigned int u = __float_as_uint(x);
    u = (u + 0x7fffu + ((u >> 16) & 1u)) >> 16;
    return (short)u;
}

// ---------------- kernel A: M = (D^-1/2 W D^-1/2)^2, stored [62][63] (pad col = 0)
__global__ __launch_bounds__(1024) void build_M(const float* __restrict__ ew,
                                                const int* __restrict__ tx,
                                                const int* __restrict__ ty,
                                                float* __restrict__ Mg) {
    __shared__ __align__(16) float W[NNODE * 64];
    __shared__ float dinv[64];
    const int t = threadIdx.x;

    for (int i = t; i < NNODE * 64; i += 1024) W[i] = 0.f;
    if (t < 64) dinv[t] = 0.f;
    __syncthreads();

    for (int e = t; e < NTRIL; e += 1024) {
        const int x = tx[e], y = ty[e];
        const float v = ew[e];
        W[x * 64 + y] = v;
        W[y * 64 + x] = v;
    }
    __syncthreads();

    // row degrees with 16 threads per row, then D^-1/2
    if (t < NNODE * 16) {
        const int r = t >> 4, j = t & 15;
        float s = 0.f;
        for (int k = j; k < NNODE; k += 16) s += fabsf(W[r * 64 + k]);
        s += __shfl_xor(s, 8);
        s += __shfl_xor(s, 4);
        s += __shfl_xor(s, 2);
        s += __shfl_xor(s, 1);
        if (j == 0) dinv[r] = (s > 0.f) ? (1.0f / sqrtf(s)) : 0.f;
    }
    __syncthreads();

    for (int i = t; i < NNODE * 64; i += 1024) {
        const int r = i >> 6, c = i & 63;
        W[i] = W[i] * dinv[r] * dinv[c];   // dinv[62..63]=0 keeps pad cols zero
    }
    __syncthreads();

    // M = Wn @ Wn ; thread owns (row r, col-quad q)
    if (t < NNODE * 16) {
        const int r = t >> 4, q = t & 15;
        float a0 = 0.f, a1 = 0.f, a2 = 0.f, a3 = 0.f;
        for (int k = 0; k < NNODE; ++k) {
            const float a = W[r * 64 + k];
            const float4 bv = *(const float4*)&W[k * 64 + q * 4];
            a0 = fmaf(a, bv.x, a0);
            a1 = fmaf(a, bv.y, a1);
            a2 = fmaf(a, bv.z, a2);
            a3 = fmaf(a, bv.w, a3);
        }
        const float v[4] = {a0, a1, a2, a3};
        #pragma unroll
        for (int j = 0; j < 4; ++j) {
            const int c = q * 4 + j;
            if (c < MST) Mg[r * MST + c] = (c < NNODE) ? v[j] : 0.f;
        }
    }
}

// ---------------- kernel B: one wave = one graph.
//  Y = M @ X[b] (fp32) -> augmented bf16 A (k=5 column of ones carries the bias)
//  h = relu(A @ lwT) via mfma_f32_16x16x32_bf16 ; pooled relu-sum fused in epilogue
//  out[b] = pooled @ fc_w + fc_b
__global__ __launch_bounds__(256) void rgnn_fwd(const float* __restrict__ X,
                                                const float* __restrict__ Mg,
                                                const float* __restrict__ lin_w,
                                                const float* __restrict__ lin_b,
                                                const float* __restrict__ fc_w,
                                                const float* __restrict__ fc_b,
                                                float* __restrict__ out, int B) {
    __shared__ float Mlds[NNODE * MST];               // 15624 B
    __shared__ __align__(16) short lwT[HID][8];       // 6400 B : [col][k], k=5 holds bias
    __shared__ float fcs[HID * 2];                    // 3200 B
    __shared__ __align__(16) float Xs[4][NNODE][8];   // 7936 B (per wave)
    __shared__ __align__(16) short Ys[4][64][8];      // 4096 B (per wave, bf16 A tiles)
    __shared__ __align__(16) short Zs[8];             // zero region for masked frag loads

    const int t = threadIdx.x;
    const int w = t >> 6;
    const int lane = t & 63;
    const int b = blockIdx.x * 4 + w;

    // cooperative block setup
    for (int i = t; i < NNODE * MST; i += 256) Mlds[i] = Mg[i];
    for (int i = t; i < HID * 8; i += 256) {
        const int c = i >> 3, k = i & 7;
        float v = 0.f;
        if (k < FIN) v = lin_w[k * HID + c];
        else if (k == FIN) v = lin_b[c];
        lwT[c][k] = f2bf(v);
    }
    for (int i = t; i < HID * 2; i += 256) fcs[i] = fc_w[i];
    if (t < 8) Zs[t] = 0;

    if (b < B) {
        const float* xb = X + (size_t)b * (NNODE * FIN);
        for (int idx = lane; idx < NNODE * FIN; idx += 64) {
            const int n = idx / FIN, f = idx - n * FIN;
            Xs[w][n][f] = xb[idx];
        }
    }
    __syncthreads();
    if (b >= B) return;   // no further block-wide barriers

    // --- Y = M @ X (fp32); lane = node
    float y0 = 0.f, y1 = 0.f, y2 = 0.f, y3 = 0.f, y4 = 0.f;
    if (lane < NNODE) {
        const float* Mr = Mlds + lane * MST;
        for (int i = 0; i < NNODE; ++i) {
            const float m = Mr[i];
            const float4 x = *(const float4*)&Xs[w][i][0];
            const float x4 = Xs[w][i][4];
            y0 = fmaf(m, x.x, y0);
            y1 = fmaf(m, x.y, y1);
            y2 = fmaf(m, x.z, y2);
            y3 = fmaf(m, x4, y4), y3 = fmaf(m, x.w, y3);  // placeholder fixed below
            y4 = fmaf(m, x4, y4);
        }
    }
    // NOTE: the line above would double-count; replaced by clean loop:
    if (lane < NNODE) {
        y0 = y1 = y2 = y3 = y4 = 0.f;
        const float* Mr = Mlds + lane * MST;
        for (int i = 0; i < NNODE; ++i) {
            const float m = Mr[i];
            const float4 x = *(const float4*)&Xs[w][i][0];
            const float x4 = Xs[w][i][4];
            y0 = fmaf(m, x.x, y0);
            y1 = fmaf(m, x.y, y1);
            y2 = fmaf(m, x.z, y2);
            y3 = fmaf(m, x.w, y3);
            y4 = fmaf(m, x4, y4);
        }
    }

    {
        const bool real = (lane < NNODE);
        bf16x8 yv;
        yv[0] = real ? f2bf(y0) : (short)0;
        yv[1] = real ? f2bf(y1) : (short)0;
        yv[2] = real ? f2bf(y2) : (short)0;
        yv[3] = real ? f2bf(y3) : (short)0;
        yv[4] = real ? f2bf(y4) : (short)0;
        yv[5] = real ? (short)0x3F80 : (short)0;   // 1.0 in bf16 -> bias row
        yv[6] = 0;
        yv[7] = 0;
        *(bf16x8*)&Ys[w][lane][0] = yv;            // same-wave write->read, no barrier needed
    }

    // --- A fragments: lanes 0-15 carry k=0..7 (real k<6), lanes 16-63 read zeros (k>=8 pad)
    const short* zp = &Zs[0];
    bf16x8 af[4];
    #pragma unroll
    for (int rt = 0; rt < 4; ++rt) {
        const short* ap = (lane < 16) ? &Ys[w][lane + 16 * rt][0] : zp;
        af[rt] = *(const bf16x8*)ap;
    }

    // --- MFMA over 25 column tiles, fused relu-pool + fc
    const int c16 = lane & 15;
    const f32x4 zero4 = {0.f, 0.f, 0.f, 0.f};
    float o0 = 0.f, o1 = 0.f;
    for (int ct = 0; ct < 25; ++ct) {
        const short* bp = (lane < 16) ? &lwT[16 * ct + c16][0] : zp;
        const bf16x8 bfr = *(const bf16x8*)bp;
        const float2 fw = *(const float2*)&fcs[(16 * ct + c16) * 2];
        const f32x4 ac0 = __builtin_amdgcn_mfma_f32_16x16x32_bf16(af[0], bfr, zero4, 0, 0, 0);
        const f32x4 ac1 = __builtin_amdgcn_mfma_f32_16x16x32_bf16(af[1], bfr, zero4, 0, 0, 0);
        const f32x4 ac2 = __builtin_amdgcn_mfma_f32_16x16x32_bf16(af[2], bfr, zero4, 0, 0, 0);
        const f32x4 ac3 = __builtin_amdgcn_mfma_f32_16x16x32_bf16(af[3], bfr, zero4, 0, 0, 0);
        float p0 = fmaxf(ac0[0], 0.f) + fmaxf(ac0[1], 0.f) + fmaxf(ac0[2], 0.f) + fmaxf(ac0[3], 0.f);
        float p1 = fmaxf(ac1[0], 0.f) + fmaxf(ac1[1], 0.f) + fmaxf(ac1[2], 0.f) + fmaxf(ac1[3], 0.f);
        float p2 = fmaxf(ac2[0], 0.f) + fmaxf(ac2[1], 0.f) + fmaxf(ac2[2], 0.f) + fmaxf(ac2[3], 0.f);
        float p3 = fmaxf(ac3[0], 0.f) + fmaxf(ac3[1], 0.f) + fmaxf(ac3[2], 0.f) + fmaxf(ac3[3], 0.f);
        float pc = (p0 + p1) + (p2 + p3);          // sum over this lane's 16 rows
        pc += __shfl_xor(pc, 16);                  // butterfly across row groups
        pc += __shfl_xor(pc, 32);                  // now pc = pooled[col] on every lane
        o0 = fmaf(pc, fw.x, o0);
        o1 = fmaf(pc, fw.y, o1);
    }
    // lanes {l, l+16, l+32, l+48} hold identical o; reduce within a 16-lane group
    o0 += __shfl_xor(o0, 8); o0 += __shfl_xor(o0, 4); o0 += __shfl_xor(o0, 2); o0 += __shfl_xor(o0, 1);
    o1 += __shfl_xor(o1, 8); o1 += __shfl_xor(o1, 4); o1 += __shfl_xor(o1, 2); o1 += __shfl_xor(o1, 1);
    if (lane == 0) {
        out[2 * b + 0] = o0 + fc_b[0];
        out[2 * b + 1] = o1 + fc_b[1];
    }
}

extern "C" void kernel_launch(void* const* d_in, const int* in_sizes, int n_in,
                              void* d_out, int out_size, void* d_ws, size_t ws_size,
                              hipStream_t stream) {
    const float* X     = (const float*)d_in[0];
    const float* ew    = (const float*)d_in[2];
    const float* lin_w = (const float*)d_in[3];
    const float* lin_b = (const float*)d_in[4];
    const float* fc_w  = (const float*)d_in[5];
    const float* fc_b  = (const float*)d_in[6];
    const int*   tx    = (const int*)d_in[9];
    const int*   ty    = (const int*)d_in[10];

    float* Mg  = (float*)d_ws;            // 62*63*4 = 15876 B
    float* out = (float*)d_out;

    const int B = in_sizes[0] / (NNODE * FIN);   // 4096

    build_M<<<1, 1024, 0, stream>>>(ew, tx, ty, Mg);
    rgnn_fwd<<<(B + 3) / 4, 256, 0, stream>>>(X, Mg, lin_w, lin_b, fc_w, fc_b, out, B);
}

// Round 3
// 42.097 us; speedup vs baseline: 2.4798x; 2.4798x over previous
//
#include <hip/hip_runtime.h>

#define NNODE 62
#define FIN 5
#define HID 400
#define NTRIL 1953
#define MST 63          // row stride of Wn (odd => per-lane row reads are 2-way/bank, free)

typedef __attribute__((ext_vector_type(8))) short bf16x8;
typedef __attribute__((ext_vector_type(4))) float f32x4;

// float -> bf16 bits, round-to-nearest-even
static __device__ __forceinline__ short f2bf(float x) {
    unsigned int u = __float_as_uint(x);
    u = (u + 0x7fffu + ((u >> 16) & 1u)) >> 16;
    return (short)u;
}

// One fused kernel: each block (4 waves) serves 4 graphs and redundantly builds
// the normalized adjacency Wn in LDS (cheap: ~20k ops, fully parallel across
// 1024 blocks — beats a serial single-block pre-kernel by ~65us of latency).
//   per wave (1 graph): Y = Wn*(Wn*X)  (fp32, lane=node)
//                       h = relu([Y|1] @ [lin_w;lin_b])  via mfma 16x16x32 bf16
//                       out = (sum_n h) @ fc_w + fc_b    (fused in MFMA epilogue)
__global__ __launch_bounds__(256) void rgnn_fused(const float* __restrict__ X,
                                                  const float* __restrict__ ew,
                                                  const int* __restrict__ tx,
                                                  const int* __restrict__ ty,
                                                  const float* __restrict__ lin_w,
                                                  const float* __restrict__ lin_b,
                                                  const float* __restrict__ fc_w,
                                                  const float* __restrict__ fc_b,
                                                  float* __restrict__ out, int B) {
    __shared__ float Wn[NNODE * MST];                 // 15624 B
    __shared__ float dinv[64];
    __shared__ __align__(16) short lwT[HID][8];       // 6400 B : [col][k], k=5 holds bias
    __shared__ float fcs[HID * 2];                    // 3200 B
    __shared__ __align__(16) float Xs[4][NNODE][8];   // 7936 B (per-wave slabs)
    __shared__ __align__(16) short Ys[4][64][8];      // 4096 B (bf16 A tiles)
    __shared__ __align__(16) short Zs[8];             // zero region for masked frag loads

    const int t = threadIdx.x;
    const int w = t >> 6;
    const int lane = t & 63;
    const int b = blockIdx.x * 4 + w;

    // ---- phase 0: zero Wn, load weights, load X ----
    for (int i = t; i < NNODE * MST; i += 256) Wn[i] = 0.f;
    if (t < 64) dinv[t] = 0.f;
    for (int i = t; i < HID * 8; i += 256) {
        const int c = i >> 3, k = i & 7;
        float v = 0.f;
        if (k < FIN) v = lin_w[k * HID + c];
        else if (k == FIN) v = lin_b[c];
        lwT[c][k] = f2bf(v);
    }
    for (int i = t; i < HID * 2; i += 256) fcs[i] = fc_w[i];
    if (t < 8) Zs[t] = 0;
    if (b < B) {
        const float* xb = X + (size_t)b * (NNODE * FIN);
        for (int idx = lane; idx < NNODE * FIN; idx += 64) {
            const int n = idx / FIN, f = idx - n * FIN;
            Xs[w][n][f] = xb[idx];
        }
    }
    __syncthreads();

    // ---- phase 1: scatter symmetric W from lower-tri params ----
    for (int e = t; e < NTRIL; e += 256) {
        const int x = tx[e], y = ty[e];
        const float v = ew[e];
        Wn[x * MST + y] = v;
        Wn[y * MST + x] = v;
    }
    __syncthreads();

    // ---- phase 2: row degrees -> D^-1/2 (4 threads per row) ----
    if (t < NNODE * 4) {
        const int r = t >> 2, j = t & 3;
        float s = 0.f;
        for (int k = j; k < NNODE; k += 4) s += fabsf(Wn[r * MST + k]);
        s += __shfl_xor(s, 2);
        s += __shfl_xor(s, 1);
        if (j == 0) dinv[r] = (s > 0.f) ? (1.0f / sqrtf(s)) : 0.f;
    }
    __syncthreads();

    // ---- phase 3: Wn = D^-1/2 W D^-1/2 ----
    for (int i = t; i < NNODE * MST; i += 256) {
        const int r = i / MST, c = i - r * MST;
        Wn[i] = Wn[i] * dinv[r] * dinv[c];   // dinv[62]=0 keeps the pad column zero
    }
    __syncthreads();

    // ---- phase 4: two propagation hops, lane = node (fp32) ----
    float y0 = 0.f, y1 = 0.f, y2 = 0.f, y3 = 0.f, y4 = 0.f;
    if (lane < NNODE) {
        const float* Wr = Wn + lane * MST;
        for (int i = 0; i < NNODE; ++i) {
            const float m = Wr[i];
            const float4 x = *(const float4*)&Xs[w][i][0];
            const float x4 = Xs[w][i][4];
            y0 = fmaf(m, x.x, y0);
            y1 = fmaf(m, x.y, y1);
            y2 = fmaf(m, x.z, y2);
            y3 = fmaf(m, x.w, y3);
            y4 = fmaf(m, x4, y4);
        }
        // write hop-1 result back into this wave's own Xs slab (no cross-wave
        // sharing; LDS pipe is in-order per wave, compiler keeps may-alias order)
        Xs[w][lane][0] = y0; Xs[w][lane][1] = y1; Xs[w][lane][2] = y2;
        Xs[w][lane][3] = y3; Xs[w][lane][4] = y4;
        y0 = y1 = y2 = y3 = y4 = 0.f;
        for (int i = 0; i < NNODE; ++i) {
            const float m = Wr[i];
            const float4 x = *(const float4*)&Xs[w][i][0];
            const float x4 = Xs[w][i][4];
            y0 = fmaf(m, x.x, y0);
            y1 = fmaf(m, x.y, y1);
            y2 = fmaf(m, x.z, y2);
            y3 = fmaf(m, x.w, y3);
            y4 = fmaf(m, x4, y4);
        }
    }

    // ---- phase 5: pack augmented bf16 A rows: [y0..y4, 1.0(bias), 0, 0] ----
    {
        const bool real = (lane < NNODE);
        bf16x8 yv;
        yv[0] = real ? f2bf(y0) : (short)0;
        yv[1] = real ? f2bf(y1) : (short)0;
        yv[2] = real ? f2bf(y2) : (short)0;
        yv[3] = real ? f2bf(y3) : (short)0;
        yv[4] = real ? f2bf(y4) : (short)0;
        yv[5] = real ? (short)0x3F80 : (short)0;   // 1.0 -> bias row; pad rows all-zero
        yv[6] = 0;
        yv[7] = 0;
        *(bf16x8*)&Ys[w][lane][0] = yv;            // same-wave produce->consume
    }

    // ---- phase 6: A fragments (lanes 0-15 carry k=0..7; k>=8 lanes read zeros) ----
    const short* zp = &Zs[0];
    bf16x8 af[4];
    #pragma unroll
    for (int rt = 0; rt < 4; ++rt) {
        const short* ap = (lane < 16) ? &Ys[w][lane + 16 * rt][0] : zp;
        af[rt] = *(const bf16x8*)ap;
    }

    // ---- phase 7: 25 col-tiles of MFMA, fused relu-pool + fc contraction ----
    const int c16 = lane & 15;
    const f32x4 zero4 = {0.f, 0.f, 0.f, 0.f};
    float o0 = 0.f, o1 = 0.f;
    for (int ct = 0; ct < 25; ++ct) {
        const short* bp = (lane < 16) ? &lwT[16 * ct + c16][0] : zp;
        const bf16x8 bfr = *(const bf16x8*)bp;
        const float2 fw = *(const float2*)&fcs[(16 * ct + c16) * 2];
        const f32x4 ac0 = __builtin_amdgcn_mfma_f32_16x16x32_bf16(af[0], bfr, zero4, 0, 0, 0);
        const f32x4 ac1 = __builtin_amdgcn_mfma_f32_16x16x32_bf16(af[1], bfr, zero4, 0, 0, 0);
        const f32x4 ac2 = __builtin_amdgcn_mfma_f32_16x16x32_bf16(af[2], bfr, zero4, 0, 0, 0);
        const f32x4 ac3 = __builtin_amdgcn_mfma_f32_16x16x32_bf16(af[3], bfr, zero4, 0, 0, 0);
        float p0 = fmaxf(ac0[0], 0.f) + fmaxf(ac0[1], 0.f) + fmaxf(ac0[2], 0.f) + fmaxf(ac0[3], 0.f);
        float p1 = fmaxf(ac1[0], 0.f) + fmaxf(ac1[1], 0.f) + fmaxf(ac1[2], 0.f) + fmaxf(ac1[3], 0.f);
        float p2 = fmaxf(ac2[0], 0.f) + fmaxf(ac2[1], 0.f) + fmaxf(ac2[2], 0.f) + fmaxf(ac2[3], 0.f);
        float p3 = fmaxf(ac3[0], 0.f) + fmaxf(ac3[1], 0.f) + fmaxf(ac3[2], 0.f) + fmaxf(ac3[3], 0.f);
        float pc = (p0 + p1) + (p2 + p3);          // this lane's 16 rows
        pc += __shfl_xor(pc, 16);
        pc += __shfl_xor(pc, 32);                  // pooled[col] on every lane
        o0 = fmaf(pc, fw.x, o0);
        o1 = fmaf(pc, fw.y, o1);
    }
    // lanes {l, l+16, l+32, l+48} hold identical o; reduce the 16-lane group
    o0 += __shfl_xor(o0, 8); o0 += __shfl_xor(o0, 4); o0 += __shfl_xor(o0, 2); o0 += __shfl_xor(o0, 1);
    o1 += __shfl_xor(o1, 8); o1 += __shfl_xor(o1, 4); o1 += __shfl_xor(o1, 2); o1 += __shfl_xor(o1, 1);
    if (lane == 0 && b < B) {
        out[2 * b + 0] = o0 + fc_b[0];
        out[2 * b + 1] = o1 + fc_b[1];
    }
}

extern "C" void kernel_launch(void* const* d_in, const int* in_sizes, int n_in,
                              void* d_out, int out_size, void* d_ws, size_t ws_size,
                              hipStream_t stream) {
    const float* X     = (const float*)d_in[0];
    const float* ew    = (const float*)d_in[2];
    const float* lin_w = (const float*)d_in[3];
    const float* lin_b = (const float*)d_in[4];
    const float* fc_w  = (const float*)d_in[5];
    const float* fc_b  = (const float*)d_in[6];
    const int*   tx    = (const int*)d_in[9];
    const int*   ty    = (const int*)d_in[10];

    float* outp = (float*)d_out;
    const int B = in_sizes[0] / (NNODE * FIN);   // 4096

    rgnn_fused<<<(B + 3) / 4, 256, 0, stream>>>(X, ew, tx, ty, lin_w, lin_b,
                                                fc_w, fc_b, outp, B);
}

// Round 4
// 34.481 us; speedup vs baseline: 3.0274x; 1.2208x over previous
//
#include <hip/hip_runtime.h>

#define NNODE 62
#define FIN 5
#define HID 400
#define NTRIL 1953
#define MST 63          // row stride of Wn (odd => per-lane row reads are 2-way/bank, free)

typedef __attribute__((ext_vector_type(8))) short bf16x8;
typedef __attribute__((ext_vector_type(4))) float f32x4;

// float -> bf16 bits, round-to-nearest-even
static __device__ __forceinline__ unsigned short f2bfu(float x) {
    unsigned int u = __float_as_uint(x);
    u = (u + 0x7fffu + ((u >> 16) & 1u)) >> 16;
    return (unsigned short)u;
}

// One fused kernel, 4 waves/block = 4 graphs/block, 1024 blocks (= 4 blocks/CU).
//   block: build Wn = D^-1/2 W D^-1/2 in LDS (redundant per block, ~cheap)
//   wave:  Y = Wn*(Wn*X)  (fp32, lane = node)
//          A-frags built in registers via shfl (no LDS round-trip)
//          h = relu([Y|1] @ [lin_w;lin_b]) via mfma 16x16x32 bf16
//          out = (sum_n h) @ fc_w + fc_b, accumulated per-lane, ONE final butterfly
__global__ __launch_bounds__(256) void rgnn_fused(const float* __restrict__ X,
                                                  const float* __restrict__ ew,
                                                  const int* __restrict__ tx,
                                                  const int* __restrict__ ty,
                                                  const float* __restrict__ lin_w,
                                                  const float* __restrict__ lin_b,
                                                  const float* __restrict__ fc_w,
                                                  const float* __restrict__ fc_b,
                                                  float* __restrict__ out, int B) {
    __shared__ float Wn[NNODE * MST];                 // 15624 B
    __shared__ float dinv[64];
    __shared__ __align__(16) short lwT[HID][8];       // 6400 B : [col][k], k=5 holds bias
    __shared__ float fcs[HID * 2];                    // 3200 B
    __shared__ __align__(16) float Xs[4][NNODE][8];   // 7936 B (per-wave slabs)
    __shared__ __align__(16) short Zs[8];             // zero region for masked frag loads

    const int t = threadIdx.x;
    const int w = t >> 6;
    const int lane = t & 63;
    const int b = blockIdx.x * 4 + w;

    // ---- phase 0: zero Wn, stage weights, load X ----
    for (int i = t; i < NNODE * MST; i += 256) Wn[i] = 0.f;
    if (t < 64) dinv[t] = 0.f;
    for (int i = t; i < HID * 8; i += 256) {
        const int c = i >> 3, k = i & 7;
        float v = 0.f;
        if (k < FIN) v = lin_w[k * HID + c];
        else if (k == FIN) v = lin_b[c];
        lwT[c][k] = (short)f2bfu(v);
    }
    for (int i = t; i < HID * 2; i += 256) fcs[i] = fc_w[i];
    if (t < 8) Zs[t] = 0;
    if (b < B) {
        const float* xb = X + (size_t)b * (NNODE * FIN);
        for (int idx = lane; idx < NNODE * FIN; idx += 64) {
            const int n = idx / FIN, f = idx - n * FIN;
            Xs[w][n][f] = xb[idx];
        }
    }
    __syncthreads();

    // ---- phase 1: scatter symmetric W from lower-tri params ----
    for (int e = t; e < NTRIL; e += 256) {
        const int x = tx[e], y = ty[e];
        const float v = ew[e];
        Wn[x * MST + y] = v;
        Wn[y * MST + x] = v;
    }
    __syncthreads();

    // ---- phase 2: row degrees -> D^-1/2 (4 threads per row) ----
    if (t < NNODE * 4) {
        const int r = t >> 2, j = t & 3;
        float s = 0.f;
        for (int k = j; k < NNODE; k += 4) s += fabsf(Wn[r * MST + k]);
        s += __shfl_xor(s, 2);
        s += __shfl_xor(s, 1);
        if (j == 0) dinv[r] = (s > 0.f) ? (1.0f / sqrtf(s)) : 0.f;
    }
    __syncthreads();

    // ---- phase 3: Wn = D^-1/2 W D^-1/2 ----
    for (int i = t; i < NNODE * MST; i += 256) {
        const int r = i / MST, c = i - r * MST;
        Wn[i] = Wn[i] * dinv[r] * dinv[c];   // dinv[62]=0 keeps the pad column zero
    }
    __syncthreads();

    // ---- phase 4: two propagation hops, lane = node (fp32) ----
    float y0 = 0.f, y1 = 0.f, y2 = 0.f, y3 = 0.f, y4 = 0.f;
    if (lane < NNODE) {
        const float* Wr = Wn + lane * MST;
        #pragma unroll 4
        for (int i = 0; i < NNODE; ++i) {
            const float m = Wr[i];
            const float4 x = *(const float4*)&Xs[w][i][0];
            const float x4 = Xs[w][i][4];
            y0 = fmaf(m, x.x, y0);
            y1 = fmaf(m, x.y, y1);
            y2 = fmaf(m, x.z, y2);
            y3 = fmaf(m, x.w, y3);
            y4 = fmaf(m, x4, y4);
        }
        // hop-1 writeback into this wave's own slab (same-wave order preserved)
        Xs[w][lane][0] = y0; Xs[w][lane][1] = y1; Xs[w][lane][2] = y2;
        Xs[w][lane][3] = y3; Xs[w][lane][4] = y4;
        y0 = y1 = y2 = y3 = y4 = 0.f;
        #pragma unroll 4
        for (int i = 0; i < NNODE; ++i) {
            const float m = Wr[i];
            const float4 x = *(const float4*)&Xs[w][i][0];
            const float x4 = Xs[w][i][4];
            y0 = fmaf(m, x.x, y0);
            y1 = fmaf(m, x.y, y1);
            y2 = fmaf(m, x.z, y2);
            y3 = fmaf(m, x.w, y3);
            y4 = fmaf(m, x4, y4);
        }
    }

    // ---- phase 5: pack augmented bf16 row [y0..y4, 1.0] into 3 dwords ----
    const bool real = (lane < NNODE);
    unsigned int q0 = 0u, q1 = 0u, q2 = 0u;
    if (real) {
        q0 = (unsigned int)f2bfu(y0) | ((unsigned int)f2bfu(y1) << 16);
        q1 = (unsigned int)f2bfu(y2) | ((unsigned int)f2bfu(y3) << 16);
        q2 = (unsigned int)f2bfu(y4) | (0x3F80u << 16);   // k=5 bias row = 1.0
    }

    // ---- phase 6: A-frags via shuffles (lanes 0-15 carry k=0..7; others zero) ----
    const int sl = lane & 15;
    const bool klive = (lane < 16);
    bf16x8 af[4];
    #pragma unroll
    for (int rt = 0; rt < 4; ++rt) {
        const unsigned int a0 = (unsigned int)__shfl((int)q0, sl + 16 * rt, 64);
        const unsigned int a1 = (unsigned int)__shfl((int)q1, sl + 16 * rt, 64);
        const unsigned int a2 = (unsigned int)__shfl((int)q2, sl + 16 * rt, 64);
        union { bf16x8 v; unsigned int u[4]; } cc;
        cc.u[0] = klive ? a0 : 0u;
        cc.u[1] = klive ? a1 : 0u;
        cc.u[2] = klive ? a2 : 0u;
        cc.u[3] = 0u;
        af[rt] = cc.v;
    }

    // ---- phase 7: 25 col-tiles of MFMA; per-lane partial fc accumulation ----
    // lane (group g=lane>>4, col c16) holds rows {16rt+4g..16rt+4g+3} of h for
    // col 16ct+c16; accumulate relu-sum * fc_w locally, reduce once at the end.
    const int c16 = lane & 15;
    const f32x4 zero4 = {0.f, 0.f, 0.f, 0.f};
    float o0 = 0.f, o1 = 0.f;
    for (int ct = 0; ct < 25; ++ct) {
        const short* bp = klive ? &lwT[16 * ct + c16][0] : &Zs[0];
        const bf16x8 bfr = *(const bf16x8*)bp;
        const float2 fw = *(const float2*)&fcs[(16 * ct + c16) * 2];
        const f32x4 ac0 = __builtin_amdgcn_mfma_f32_16x16x32_bf16(af[0], bfr, zero4, 0, 0, 0);
        const f32x4 ac1 = __builtin_amdgcn_mfma_f32_16x16x32_bf16(af[1], bfr, zero4, 0, 0, 0);
        const f32x4 ac2 = __builtin_amdgcn_mfma_f32_16x16x32_bf16(af[2], bfr, zero4, 0, 0, 0);
        const f32x4 ac3 = __builtin_amdgcn_mfma_f32_16x16x32_bf16(af[3], bfr, zero4, 0, 0, 0);
        float p0 = fmaxf(ac0[0], 0.f) + fmaxf(ac0[1], 0.f) + fmaxf(ac0[2], 0.f) + fmaxf(ac0[3], 0.f);
        float p1 = fmaxf(ac1[0], 0.f) + fmaxf(ac1[1], 0.f) + fmaxf(ac1[2], 0.f) + fmaxf(ac1[3], 0.f);
        float p2 = fmaxf(ac2[0], 0.f) + fmaxf(ac2[1], 0.f) + fmaxf(ac2[2], 0.f) + fmaxf(ac2[3], 0.f);
        float p3 = fmaxf(ac3[0], 0.f) + fmaxf(ac3[1], 0.f) + fmaxf(ac3[2], 0.f) + fmaxf(ac3[3], 0.f);
        const float pc = (p0 + p1) + (p2 + p3);   // this lane's 16 rows, col 16ct+c16
        o0 = fmaf(pc, fw.x, o0);
        o1 = fmaf(pc, fw.y, o1);
    }
    // single full-wave butterfly: sums over all (row-group, col) partials
    #pragma unroll
    for (int s = 32; s > 0; s >>= 1) {
        o0 += __shfl_xor(o0, s, 64);
        o1 += __shfl_xor(o1, s, 64);
    }
    if (lane == 0 && b < B) {
        out[2 * b + 0] = o0 + fc_b[0];
        out[2 * b + 1] = o1 + fc_b[1];
    }
}

extern "C" void kernel_launch(void* const* d_in, const int* in_sizes, int n_in,
                              void* d_out, int out_size, void* d_ws, size_t ws_size,
                              hipStream_t stream) {
    const float* X     = (const float*)d_in[0];
    const float* ew    = (const float*)d_in[2];
    const float* lin_w = (const float*)d_in[3];
    const float* lin_b = (const float*)d_in[4];
    const float* fc_w  = (const float*)d_in[5];
    const float* fc_b  = (const float*)d_in[6];
    const int*   tx    = (const int*)d_in[9];
    const int*   ty    = (const int*)d_in[10];

    float* outp = (float*)d_out;
    const int B = in_sizes[0] / (NNODE * FIN);   // 4096

    rgnn_fused<<<(B + 3) / 4, 256, 0, stream>>>(X, ew, tx, ty, lin_w, lin_b,
                                                fc_w, fc_b, outp, B);
}

// Round 5
// 23.586 us; speedup vs baseline: 4.4259x; 1.4619x over previous
//
#include <hip/hip_runtime.h>
#include <hip/hip_bf16.h>

#define NNODE 62
#define FIN 5
#define HID 400
#define NTRIL 1953
#define MST 63          // f32 Wn row stride (odd => conflict-free scalar column/row access)
#define WST 72          // XT row stride in shorts (144B: 16B-aligned, ~2-way banks on b128)
#define WAVES 8

typedef __attribute__((ext_vector_type(8))) short bf16x8;
typedef __attribute__((ext_vector_type(4))) float f32x4;

// f32 -> bf16 (RNE) via HW cvt; compiler pairs these into v_cvt_pk_bf16_f32
static __device__ __forceinline__ short f2bf(float x) {
    __hip_bfloat16 h = __float2bfloat16(x);
    return *reinterpret_cast<short*>(&h);
}

// One dispatch. 512-thread blocks = 8 waves = 8 graphs; block builds Wn once.
//   hops:  Y2 = Wn*(Wn*X) as 2x (8 MFMA 16x16x32 bf16), W-frags cached in VGPRs
//   lin:   h = relu([Y2|1] @ [lin_w;lin_b]) via MFMA (round-4 proven loop)
//   out:   (sum_n h) @ fc_w + fc_b, per-lane partials, one final butterfly
__global__ __launch_bounds__(512, 4) void rgnn_fused(
        const float* __restrict__ X,     const float* __restrict__ ew,
        const int* __restrict__ tx,      const int* __restrict__ ty,
        const float* __restrict__ lin_w, const float* __restrict__ lin_b,
        const float* __restrict__ fc_w,  const float* __restrict__ fc_b,
        float* __restrict__ out, int B) {
    __shared__ float Wn[NNODE * MST];                  // 15624 B
    __shared__ float dinv[64];
    __shared__ __align__(16) short Wfrag[8][64][8];    // 8192 B: [rt*2+ks][lane][j] A-frags
    __shared__ __align__(16) short lwT[HID][8];        // 6400 B: [col][k], k=5 carries bias
    __shared__ float fcs[HID * 2];                     // 3200 B
    __shared__ __align__(16) short XT[WAVES][FIN][WST];// 5760 B: X^T then Y1^T, bf16
    __shared__ __align__(16) short Y2A[WAVES][64][8];  // 8192 B: lin A rows, k=5 bias=1
    __shared__ __align__(16) short Zs[8];              // zero row for masked frag loads

    const int t = threadIdx.x;
    const int w = t >> 6;
    const int lane = t & 63;
    const int b = blockIdx.x * WAVES + w;

    // ---- phase 0: zero/stage block-shared state ----
    for (int i = t; i < NNODE * MST; i += 512) Wn[i] = 0.f;
    if (t < 64) dinv[t] = 0.f;
    for (int i = t; i < HID * 8; i += 512) {
        const int c = i >> 3, k = i & 7;
        float v = 0.f;
        if (k < FIN) v = lin_w[k * HID + c];
        else if (k == FIN) v = lin_b[c];
        lwT[c][k] = f2bf(v);
    }
    for (int i = t; i < HID * 2; i += 512) fcs[i] = fc_w[i];
    if (t < 8) Zs[t] = 0;
    for (int i = t; i < WAVES * 64 * 8; i += 512) {    // Y2A: bias col ones (real rows only)
        const int n = (i >> 3) & 63, k = i & 7;
        ((short*)Y2A)[i] = (k == FIN && n < NNODE) ? (short)0x3F80 : (short)0;
    }
    for (int i = t; i < WAVES * FIN * WST; i += 512) ((short*)XT)[i] = 0;
    __syncthreads();

    // ---- phase 1: scatter symmetric W; per-wave X load (transposed bf16) ----
    for (int e = t; e < NTRIL; e += 512) {
        const int x = tx[e], y = ty[e];
        const float v = ew[e];
        Wn[x * MST + y] = v;
        Wn[y * MST + x] = v;
    }
    if (b < B) {
        const float* xb = X + (size_t)b * (NNODE * FIN);
        for (int idx = lane; idx < NNODE * FIN; idx += 64) {
            const int n = idx / FIN, f = idx - n * FIN;
            XT[w][f][n] = f2bf(xb[idx]);
        }
    }
    __syncthreads();

    // ---- phase 2: row degrees -> D^-1/2 (8 threads per row) ----
    if (t < NNODE * 8) {
        const int r = t >> 3, j = t & 7;
        float s = 0.f;
        for (int k = j; k < NNODE; k += 8) s += fabsf(Wn[r * MST + k]);
        s += __shfl_xor(s, 4);
        s += __shfl_xor(s, 2);
        s += __shfl_xor(s, 1);
        if (j == 0) dinv[r] = (s > 0.f) ? (1.0f / sqrtf(s)) : 0.f;
    }
    __syncthreads();

    // ---- phase 3: Wn = D^-1/2 W D^-1/2 ----
    for (int i = t; i < NNODE * MST; i += 512) {
        const int r = i / MST, c = i - r * MST;
        Wn[i] = Wn[i] * dinv[r] * dinv[c];
    }
    __syncthreads();

    // ---- phase 3b: A-fragment-order bf16 copy of Wn (one frag-row per thread) ----
    {
        const int fi = t >> 6, l = t & 63;           // fi = rt*2 + ks
        const int rt = fi >> 1, ks = fi & 1;
        const int row = (l & 15) + 16 * rt;          // A: row = lane&15
        const int k0 = ks * 32 + (l >> 4) * 8;       //    k = kgroup(lane>>4)*8 + j
        union { short s[8]; bf16x8 v8; } u;
        #pragma unroll
        for (int j = 0; j < 8; ++j) {
            const int k = k0 + j;
            u.s[j] = (row < NNODE && k < NNODE) ? f2bf(Wn[row * MST + k]) : (short)0;
        }
        *(bf16x8*)&Wfrag[fi][l][0] = u.v8;
    }
    __syncthreads();    // last block-wide barrier

    if (b >= B) return;

    // ---- phase 4: cache W A-frags in VGPRs (linear lane-major b128 reads) ----
    bf16x8 wf[8];
    #pragma unroll
    for (int fi = 0; fi < 8; ++fi) wf[fi] = *(const bf16x8*)&Wfrag[fi][lane][0];

    const int f16 = lane & 15;        // hop: B col (feature) / lin: hidden col
    const int g   = lane >> 4;        // k-group
    const bool freal = (f16 < FIN);
    const short* zp = &Zs[0];
    const f32x4 z4 = {0.f, 0.f, 0.f, 0.f};

    // hop 1: Y1 = Wn @ X
    bf16x8 bx0, bx1;
    {
        const short* p0 = freal ? &XT[w][f16][g * 8]      : zp;
        const short* p1 = freal ? &XT[w][f16][32 + g * 8] : zp;
        bx0 = *(const bf16x8*)p0;
        bx1 = *(const bf16x8*)p1;
    }
    f32x4 acc[4];
    #pragma unroll
    for (int rt = 0; rt < 4; ++rt) {
        acc[rt] = __builtin_amdgcn_mfma_f32_16x16x32_bf16(wf[rt * 2 + 0], bx0, z4, 0, 0, 0);
        acc[rt] = __builtin_amdgcn_mfma_f32_16x16x32_bf16(wf[rt * 2 + 1], bx1, acc[rt], 0, 0, 0);
    }
    // write Y1^T back into XT (packed pairs; same-wave LDS is in-order: reads above
    // were already issued, so reusing the buffer is hazard-free — round-3-proven)
    if (freal) {
        #pragma unroll
        for (int rt = 0; rt < 4; ++rt) {
            const int n0 = rt * 16 + g * 4;          // D: row = (lane>>4)*4 + reg (+16rt)
            const unsigned int d0 = (unsigned short)f2bf(acc[rt][0]) |
                                    ((unsigned int)(unsigned short)f2bf(acc[rt][1]) << 16);
            const unsigned int d1 = (unsigned short)f2bf(acc[rt][2]) |
                                    ((unsigned int)(unsigned short)f2bf(acc[rt][3]) << 16);
            if (n0 + 1 < NNODE) *(unsigned int*)&XT[w][f16][n0] = d0;
            if (n0 + 3 < NNODE) *(unsigned int*)&XT[w][f16][n0 + 2] = d1;
        }
    }

    // hop 2: Y2 = Wn @ Y1 (same W frags from registers)
    {
        const short* p0 = freal ? &XT[w][f16][g * 8]      : zp;
        const short* p1 = freal ? &XT[w][f16][32 + g * 8] : zp;
        bx0 = *(const bf16x8*)p0;
        bx1 = *(const bf16x8*)p1;
    }
    #pragma unroll
    for (int rt = 0; rt < 4; ++rt) {
        acc[rt] = __builtin_amdgcn_mfma_f32_16x16x32_bf16(wf[rt * 2 + 0], bx0, z4, 0, 0, 0);
        acc[rt] = __builtin_amdgcn_mfma_f32_16x16x32_bf16(wf[rt * 2 + 1], bx1, acc[rt], 0, 0, 0);
    }
    // scatter Y2 -> Y2A[node][f] (bias col/pad rows pre-initialized in phase 0)
    if (freal) {
        #pragma unroll
        for (int rt = 0; rt < 4; ++rt) {
            const int n0 = rt * 16 + g * 4;
            #pragma unroll
            for (int r = 0; r < 4; ++r) {
                if (n0 + r < NNODE) Y2A[w][n0 + r][f16] = f2bf(acc[rt][r]);
            }
        }
    }

    // ---- phase 5: lin A-frags from Y2A (same-wave in-order LDS) ----
    bf16x8 af[4];
    #pragma unroll
    for (int rt = 0; rt < 4; ++rt) {
        const short* ap = (lane < 16) ? &Y2A[w][lane + 16 * rt][0] : zp;
        af[rt] = *(const bf16x8*)ap;
    }

    // ---- phase 6: 25 col-tiles of MFMA; per-lane partial fc accumulation ----
    float o0 = 0.f, o1 = 0.f;
    for (int ct = 0; ct < 25; ++ct) {
        const short* bp = (lane < 16) ? &lwT[16 * ct + f16][0] : zp;
        const bf16x8 bfr = *(const bf16x8*)bp;
        const float2 fw = *(const float2*)&fcs[(16 * ct + f16) * 2];
        const f32x4 ac0 = __builtin_amdgcn_mfma_f32_16x16x32_bf16(af[0], bfr, z4, 0, 0, 0);
        const f32x4 ac1 = __builtin_amdgcn_mfma_f32_16x16x32_bf16(af[1], bfr, z4, 0, 0, 0);
        const f32x4 ac2 = __builtin_amdgcn_mfma_f32_16x16x32_bf16(af[2], bfr, z4, 0, 0, 0);
        const f32x4 ac3 = __builtin_amdgcn_mfma_f32_16x16x32_bf16(af[3], bfr, z4, 0, 0, 0);
        float p0 = fmaxf(ac0[0], 0.f) + fmaxf(ac0[1], 0.f) + fmaxf(ac0[2], 0.f) + fmaxf(ac0[3], 0.f);
        float p1 = fmaxf(ac1[0], 0.f) + fmaxf(ac1[1], 0.f) + fmaxf(ac1[2], 0.f) + fmaxf(ac1[3], 0.f);
        float p2 = fmaxf(ac2[0], 0.f) + fmaxf(ac2[1], 0.f) + fmaxf(ac2[2], 0.f) + fmaxf(ac2[3], 0.f);
        float p3 = fmaxf(ac3[0], 0.f) + fmaxf(ac3[1], 0.f) + fmaxf(ac3[2], 0.f) + fmaxf(ac3[3], 0.f);
        const float pc = (p0 + p1) + (p2 + p3);    // 16 rows of col 16ct+f16
        o0 = fmaf(pc, fw.x, o0);
        o1 = fmaf(pc, fw.y, o1);
    }
    // one full-wave butterfly over (row-group, col) partials
    #pragma unroll
    for (int s = 32; s > 0; s >>= 1) {
        o0 += __shfl_xor(o0, s, 64);
        o1 += __shfl_xor(o1, s, 64);
    }
    if (lane == 0) {
        out[2 * b + 0] = o0 + fc_b[0];
        out[2 * b + 1] = o1 + fc_b[1];
    }
}

extern "C" void kernel_launch(void* const* d_in, const int* in_sizes, int n_in,
                              void* d_out, int out_size, void* d_ws, size_t ws_size,
                              hipStream_t stream) {
    const float* X     = (const float*)d_in[0];
    const float* ew    = (const float*)d_in[2];
    const float* lin_w = (const float*)d_in[3];
    const float* lin_b = (const float*)d_in[4];
    const float* fc_w  = (const float*)d_in[5];
    const float* fc_b  = (const float*)d_in[6];
    const int*   tx    = (const int*)d_in[9];
    const int*   ty    = (const int*)d_in[10];

    float* outp = (float*)d_out;
    const int B = in_sizes[0] / (NNODE * FIN);   // 4096

    rgnn_fused<<<(B + WAVES - 1) / WAVES, 512, 0, stream>>>(
        X, ew, tx, ty, lin_w, lin_b, fc_w, fc_b, outp, B);
}

// Round 6
// 22.105 us; speedup vs baseline: 4.7225x; 1.0670x over previous
//
#include <hip/hip_runtime.h>
#include <hip/hip_bf16.h>

#define NNODE 62
#define FIN 5
#define HID 400
#define NTRIL 1953
#define MST 63          // f32 Wn row stride
#define WST 72          // XT row stride in shorts (144B)
#define WAVES 8
#define GPW 2           // graphs per wave

typedef __attribute__((ext_vector_type(8))) short bf16x8;
typedef __attribute__((ext_vector_type(4))) float f32x4;

static __device__ __forceinline__ short f2bf(float x) {
    __hip_bfloat16 h = __float2bfloat16(x);
    return *reinterpret_cast<short*>(&h);
}

// One dispatch, 256 blocks x 512 threads; each wave serves TWO graphs.
//   hops: both graphs share one MFMA pass (g0 in B-cols 0-4, g1 in cols 8-12)
//   lin:  h = relu([Y2|1]@[lin_w;lin_b]) per graph, interleaved chains (2x ILP)
//   out:  per-lane fc partials, one butterfly per output value
__global__ __launch_bounds__(512, 2) void rgnn_fused(
        const float* __restrict__ X,     const float* __restrict__ ew,
        const int* __restrict__ tx,      const int* __restrict__ ty,
        const float* __restrict__ lin_w, const float* __restrict__ lin_b,
        const float* __restrict__ fc_w,  const float* __restrict__ fc_b,
        float* __restrict__ out, int B) {
    __shared__ float Wn[NNODE * MST];                       // 15624 B (no zero-init: scatter covers all 62x62)
    __shared__ float dinv[NNODE];
    __shared__ __align__(16) short Wfrag[8][64][8];         // 8192 B: A-frag order, normalized bf16
    __shared__ __align__(16) short lwT[HID][8];             // 6400 B: [col][k], k=5 carries bias
    __shared__ float fcs[HID * 2];                          // 3200 B
    __shared__ __align__(16) short XT[WAVES][GPW][FIN][WST];// 11520 B: X^T then Y1^T
    __shared__ __align__(16) short Y2A[WAVES][GPW][64][8];  // 16384 B: lin A rows (fully written in scatter)
    __shared__ __align__(16) short Zs[8];

    const int t = threadIdx.x;
    const int w = t >> 6;
    const int lane = t & 63;
    const int bbase = blockIdx.x * (WAVES * GPW) + w * GPW;

    // ---- phase 0: stage weights, scatter W, load X (single barrier region) ----
    for (int i = t; i < HID * 8; i += 512) {
        const int c = i >> 3, k = i & 7;
        float v = 0.f;
        if (k < FIN) v = lin_w[k * HID + c];
        else if (k == FIN) v = lin_b[c];
        lwT[c][k] = f2bf(v);
    }
    for (int i = t; i < HID * 2; i += 512) fcs[i] = fc_w[i];
    if (t < 8) Zs[t] = 0;
    for (int e = t; e < NTRIL; e += 512) {
        const int x = tx[e], y = ty[e];
        const float v = ew[e];
        Wn[x * MST + y] = v;
        Wn[y * MST + x] = v;
    }
    #pragma unroll
    for (int gg = 0; gg < GPW; ++gg) {
        const int b = bbase + gg;
        if (b < B) {
            const float* xb = X + (size_t)b * (NNODE * FIN);
            for (int idx = lane; idx < NNODE * FIN; idx += 64) {
                const int n = idx / FIN, f = idx - n * FIN;
                XT[w][gg][f][n] = f2bf(xb[idx]);
            }
        }
    }
    if (lane < GPW * FIN) {      // zero node-pad 62,63 of each XT row (B-frags read k<64)
        const int gg = lane / FIN, f = lane - gg * FIN;
        *(unsigned int*)&XT[w][gg][f][62] = 0u;
    }
    __syncthreads();

    // ---- phase 1: row degrees -> D^-1/2 (8 threads per row) ----
    if (t < NNODE * 8) {
        const int r = t >> 3, j = t & 7;
        float s = 0.f;
        for (int k = j; k < NNODE; k += 8) s += fabsf(Wn[r * MST + k]);
        s += __shfl_xor(s, 4);
        s += __shfl_xor(s, 2);
        s += __shfl_xor(s, 1);
        if (j == 0) dinv[r] = (s > 0.f) ? (1.0f / sqrtf(s)) : 0.f;
    }
    __syncthreads();

    // ---- phase 2: normalize + convert into A-frag order in one pass ----
    {
        const int fi = t >> 6, l = t & 63;           // fi = rt*2 + ks
        const int rt = fi >> 1, ks = fi & 1;
        const int row = (l & 15) + 16 * rt;
        const int k0 = ks * 32 + (l >> 4) * 8;
        union { short s[8]; bf16x8 v8; } u;
        #pragma unroll
        for (int j = 0; j < 8; ++j) {
            const int k = k0 + j;
            u.s[j] = (row < NNODE && k < NNODE)
                   ? f2bf(Wn[row * MST + k] * dinv[row] * dinv[k]) : (short)0;
        }
        *(bf16x8*)&Wfrag[fi][l][0] = u.v8;
    }
    __syncthreads();    // last block-wide barrier

    if (bbase >= B) return;

    // ---- per-wave compute: cache W A-frags in VGPRs ----
    bf16x8 wf[8];
    #pragma unroll
    for (int fi = 0; fi < 8; ++fi) wf[fi] = *(const bf16x8*)&Wfrag[fi][lane][0];

    const int f16 = lane & 15;
    const int g   = lane >> 4;
    const int dsel = f16 >> 3;            // which graph this B/D column belongs to
    const int dk   = f16 & 7;             // k slot within that graph
    const bool fr  = (dk < FIN);          // feature column (cols 5-7,13-15 are spares)
    const short* zp = &Zs[0];
    const f32x4 z4 = {0.f, 0.f, 0.f, 0.f};

    // hop 1: Y1 = Wn @ X for BOTH graphs in one MFMA pass
    bf16x8 bx0, bx1;
    {
        const short* p0 = fr ? &XT[w][dsel][dk][g * 8]      : zp;
        const short* p1 = fr ? &XT[w][dsel][dk][32 + g * 8] : zp;
        bx0 = *(const bf16x8*)p0;
        bx1 = *(const bf16x8*)p1;
    }
    f32x4 acc[4];
    #pragma unroll
    for (int rt = 0; rt < 4; ++rt) {
        acc[rt] = __builtin_amdgcn_mfma_f32_16x16x32_bf16(wf[rt * 2 + 0], bx0, z4, 0, 0, 0);
        acc[rt] = __builtin_amdgcn_mfma_f32_16x16x32_bf16(wf[rt * 2 + 1], bx1, acc[rt], 0, 0, 0);
    }
    if (fr) {   // Y1^T writeback (same-wave in-order LDS, round-5-proven)
        #pragma unroll
        for (int rt = 0; rt < 4; ++rt) {
            const int n0 = rt * 16 + g * 4;
            const unsigned int d0 = (unsigned short)f2bf(acc[rt][0]) |
                                    ((unsigned int)(unsigned short)f2bf(acc[rt][1]) << 16);
            const unsigned int d1 = (unsigned short)f2bf(acc[rt][2]) |
                                    ((unsigned int)(unsigned short)f2bf(acc[rt][3]) << 16);
            if (n0 + 1 < NNODE) *(unsigned int*)&XT[w][dsel][dk][n0] = d0;
            if (n0 + 3 < NNODE) *(unsigned int*)&XT[w][dsel][dk][n0 + 2] = d1;
        }
    }

    // hop 2: Y2 = Wn @ Y1
    {
        const short* p0 = fr ? &XT[w][dsel][dk][g * 8]      : zp;
        const short* p1 = fr ? &XT[w][dsel][dk][32 + g * 8] : zp;
        bx0 = *(const bf16x8*)p0;
        bx1 = *(const bf16x8*)p1;
    }
    #pragma unroll
    for (int rt = 0; rt < 4; ++rt) {
        acc[rt] = __builtin_amdgcn_mfma_f32_16x16x32_bf16(wf[rt * 2 + 0], bx0, z4, 0, 0, 0);
        acc[rt] = __builtin_amdgcn_mfma_f32_16x16x32_bf16(wf[rt * 2 + 1], bx1, acc[rt], 0, 0, 0);
    }
    // scatter Y2 with FULL Y2A coverage (features, bias=1 col, zero pads) — no init pass
    #pragma unroll
    for (int rt = 0; rt < 4; ++rt) {
        const int n0 = rt * 16 + g * 4;
        #pragma unroll
        for (int r = 0; r < 4; ++r) {
            const int n = n0 + r;
            short val = 0;
            if (n < NNODE) {
                val = (dk < FIN) ? f2bf(acc[rt][r])
                                 : ((dk == FIN) ? (short)0x3F80 : (short)0);
            }
            Y2A[w][dsel][n][dk] = val;
        }
    }

    // ---- lin A-frags for both graphs (same-wave in-order LDS) ----
    bf16x8 af0[4], af1[4];
    #pragma unroll
    for (int rt = 0; rt < 4; ++rt) {
        const short* a0 = (lane < 16) ? &Y2A[w][0][lane + 16 * rt][0] : zp;
        const short* a1 = (lane < 16) ? &Y2A[w][1][lane + 16 * rt][0] : zp;
        af0[rt] = *(const bf16x8*)a0;
        af1[rt] = *(const bf16x8*)a1;
    }

    // ---- 25 col-tiles: 8 MFMA/tile (2 independent graph chains), fused relu-pool+fc ----
    float o0a = 0.f, o1a = 0.f, o0b = 0.f, o1b = 0.f;
    for (int ct = 0; ct < 25; ++ct) {
        const short* bp = (lane < 16) ? &lwT[16 * ct + f16][0] : zp;
        const bf16x8 bfr = *(const bf16x8*)bp;
        const float2 fw = *(const float2*)&fcs[(16 * ct + f16) * 2];
        const f32x4 a0 = __builtin_amdgcn_mfma_f32_16x16x32_bf16(af0[0], bfr, z4, 0, 0, 0);
        const f32x4 b0 = __builtin_amdgcn_mfma_f32_16x16x32_bf16(af1[0], bfr, z4, 0, 0, 0);
        const f32x4 a1 = __builtin_amdgcn_mfma_f32_16x16x32_bf16(af0[1], bfr, z4, 0, 0, 0);
        const f32x4 b1 = __builtin_amdgcn_mfma_f32_16x16x32_bf16(af1[1], bfr, z4, 0, 0, 0);
        const f32x4 a2 = __builtin_amdgcn_mfma_f32_16x16x32_bf16(af0[2], bfr, z4, 0, 0, 0);
        const f32x4 b2 = __builtin_amdgcn_mfma_f32_16x16x32_bf16(af1[2], bfr, z4, 0, 0, 0);
        const f32x4 a3 = __builtin_amdgcn_mfma_f32_16x16x32_bf16(af0[3], bfr, z4, 0, 0, 0);
        const f32x4 b3 = __builtin_amdgcn_mfma_f32_16x16x32_bf16(af1[3], bfr, z4, 0, 0, 0);
        float pa0 = fmaxf(a0[0],0.f)+fmaxf(a0[1],0.f)+fmaxf(a0[2],0.f)+fmaxf(a0[3],0.f);
        float pa1 = fmaxf(a1[0],0.f)+fmaxf(a1[1],0.f)+fmaxf(a1[2],0.f)+fmaxf(a1[3],0.f);
        float pa2 = fmaxf(a2[0],0.f)+fmaxf(a2[1],0.f)+fmaxf(a2[2],0.f)+fmaxf(a2[3],0.f);
        float pa3 = fmaxf(a3[0],0.f)+fmaxf(a3[1],0.f)+fmaxf(a3[2],0.f)+fmaxf(a3[3],0.f);
        float pb0 = fmaxf(b0[0],0.f)+fmaxf(b0[1],0.f)+fmaxf(b0[2],0.f)+fmaxf(b0[3],0.f);
        float pb1 = fmaxf(b1[0],0.f)+fmaxf(b1[1],0.f)+fmaxf(b1[2],0.f)+fmaxf(b1[3],0.f);
        float pb2 = fmaxf(b2[0],0.f)+fmaxf(b2[1],0.f)+fmaxf(b2[2],0.f)+fmaxf(b2[3],0.f);
        float pb3 = fmaxf(b3[0],0.f)+fmaxf(b3[1],0.f)+fmaxf(b3[2],0.f)+fmaxf(b3[3],0.f);
        const float pca = (pa0 + pa1) + (pa2 + pa3);
        const float pcb = (pb0 + pb1) + (pb2 + pb3);
        o0a = fmaf(pca, fw.x, o0a);
        o1a = fmaf(pca, fw.y, o1a);
        o0b = fmaf(pcb, fw.x, o0b);
        o1b = fmaf(pcb, fw.y, o1b);
    }
    #pragma unroll
    for (int s = 32; s > 0; s >>= 1) {
        o0a += __shfl_xor(o0a, s, 64);
        o1a += __shfl_xor(o1a, s, 64);
        o0b += __shfl_xor(o0b, s, 64);
        o1b += __shfl_xor(o1b, s, 64);
    }
    if (lane == 0) {
        out[2 * bbase + 0] = o0a + fc_b[0];
        out[2 * bbase + 1] = o1a + fc_b[1];
        if (bbase + 1 < B) {
            out[2 * bbase + 2] = o0b + fc_b[0];
            out[2 * bbase + 3] = o1b + fc_b[1];
        }
    }
}

extern "C" void kernel_launch(void* const* d_in, const int* in_sizes, int n_in,
                              void* d_out, int out_size, void* d_ws, size_t ws_size,
                              hipStream_t stream) {
    const float* X     = (const float*)d_in[0];
    const float* ew    = (const float*)d_in[2];
    const float* lin_w = (const float*)d_in[3];
    const float* lin_b = (const float*)d_in[4];
    const float* fc_w  = (const float*)d_in[5];
    const float* fc_b  = (const float*)d_in[6];
    const int*   tx    = (const int*)d_in[9];
    const int*   ty    = (const int*)d_in[10];

    float* outp = (float*)d_out;
    const int B = in_sizes[0] / (NNODE * FIN);   // 4096

    const int gpb = WAVES * GPW;                 // 16 graphs per block
    rgnn_fused<<<(B + gpb - 1) / gpb, 512, 0, stream>>>(
        X, ew, tx, ty, lin_w, lin_b, fc_w, fc_b, outp, B);
}

// Round 7
// 20.882 us; speedup vs baseline: 4.9990x; 1.0586x over previous
//
#include <hip/hip_runtime.h>
#include <hip/hip_bf16.h>

#define NNODE 62
#define FIN 5
#define HID 400
#define NTRIL 1953
#define MST 63          // f32 Wn row stride
#define WST 72          // XT row stride in shorts (144B)
#define WAVES 16        // 1024-thread block, 1 graph per wave, 1 block per CU

typedef __attribute__((ext_vector_type(8))) short bf16x8;
typedef __attribute__((ext_vector_type(4))) float f32x4;

static __device__ __forceinline__ short f2bf(float x) {
    __hip_bfloat16 h = __float2bfloat16(x);
    return *reinterpret_cast<short*>(&h);
}

// One dispatch: 256 blocks x 1024 threads (16 waves) = 1 block/CU, 4 waves/SIMD.
// Block builds Wn/Wfrag/lwT once (256 total setup instances); each wave then
// independently computes one graph: MFMA hops -> MFMA lin -> fused relu-pool+fc.
__global__ __launch_bounds__(1024, 4) void rgnn_fused(
        const float* __restrict__ X,     const float* __restrict__ ew,
        const int* __restrict__ tx,      const int* __restrict__ ty,
        const float* __restrict__ lin_w, const float* __restrict__ lin_b,
        const float* __restrict__ fc_w,  const float* __restrict__ fc_b,
        float* __restrict__ out, int B) {
    __shared__ float Wn[NNODE * MST];                   // 15624 B (scatter covers all entries)
    __shared__ float dinv[64];
    __shared__ __align__(16) short Wfrag[8][64][8];     // 8192 B: A-frag order, normalized bf16
    __shared__ __align__(16) short lwT[HID][8];         // 6400 B: [col][k], k=5 carries bias
    __shared__ float fcs[HID * 2];                      // 3200 B
    __shared__ __align__(16) short XT[WAVES][FIN][WST]; // 11520 B: X^T then Y1^T
    __shared__ __align__(16) short Y2A[WAVES][64][8];   // 16384 B: lin A rows
    __shared__ __align__(16) short Zs[8];               // total ~61.5 KB

    const int t = threadIdx.x;
    const int w = t >> 6;
    const int lane = t & 63;
    const int b = blockIdx.x * WAVES + w;

    // ---- phase 0: stage weights, scatter W, load X (one barrier region) ----
    for (int i = t; i < HID * 8; i += 1024) {
        const int c = i >> 3, k = i & 7;
        float v = 0.f;
        if (k < FIN) v = lin_w[k * HID + c];
        else if (k == FIN) v = lin_b[c];
        lwT[c][k] = f2bf(v);
    }
    for (int i = t; i < HID * 2; i += 1024) fcs[i] = fc_w[i];
    if (t < 8) Zs[t] = 0;
    for (int e = t; e < NTRIL; e += 1024) {
        const int x = tx[e], y = ty[e];
        const float v = ew[e];
        Wn[x * MST + y] = v;
        Wn[y * MST + x] = v;
    }
    if (b < B) {
        const float* xb = X + (size_t)b * (NNODE * FIN);
        for (int idx = lane; idx < NNODE * FIN; idx += 64) {
            const int n = idx / FIN, f = idx - n * FIN;
            XT[w][f][n] = f2bf(xb[idx]);
        }
        if (lane < FIN) *(unsigned int*)&XT[w][lane][62] = 0u;   // node pads 62,63
    }
    __syncthreads();

    // ---- phase 1: row degrees -> D^-1/2 (16 threads per row) ----
    if (t < NNODE * 16) {
        const int r = t >> 4, j = t & 15;
        float s = 0.f;
        for (int k = j; k < NNODE; k += 16) s += fabsf(Wn[r * MST + k]);
        s += __shfl_xor(s, 8);
        s += __shfl_xor(s, 4);
        s += __shfl_xor(s, 2);
        s += __shfl_xor(s, 1);
        if (j == 0) dinv[r] = (s > 0.f) ? (1.0f / sqrtf(s)) : 0.f;
    }
    __syncthreads();

    // ---- phase 2: normalize + convert into A-frag order (threads 0-511) ----
    if (t < 512) {
        const int fi = t >> 6, l = t & 63;           // fi = rt*2 + ks
        const int rt = fi >> 1, ks = fi & 1;
        const int row = (l & 15) + 16 * rt;
        const int k0 = ks * 32 + (l >> 4) * 8;
        union { short s[8]; bf16x8 v8; } u;
        #pragma unroll
        for (int j = 0; j < 8; ++j) {
            const int k = k0 + j;
            u.s[j] = (row < NNODE && k < NNODE)
                   ? f2bf(Wn[row * MST + k] * dinv[row] * dinv[k]) : (short)0;
        }
        *(bf16x8*)&Wfrag[fi][l][0] = u.v8;
    }
    __syncthreads();    // last block-wide barrier

    if (b >= B) return;

    // ---- per-wave: cache W A-frags in VGPRs (linear lane-major b128 reads) ----
    bf16x8 wf[8];
    #pragma unroll
    for (int fi = 0; fi < 8; ++fi) wf[fi] = *(const bf16x8*)&Wfrag[fi][lane][0];

    const int f16 = lane & 15;
    const int g   = lane >> 4;
    const bool fr = (f16 < FIN);
    const short* zp = &Zs[0];
    const f32x4 z4 = {0.f, 0.f, 0.f, 0.f};

    // hop 1: Y1 = Wn @ X
    bf16x8 bx0, bx1;
    {
        const short* p0 = fr ? &XT[w][f16][g * 8]      : zp;
        const short* p1 = fr ? &XT[w][f16][32 + g * 8] : zp;
        bx0 = *(const bf16x8*)p0;
        bx1 = *(const bf16x8*)p1;
    }
    f32x4 acc[4];
    #pragma unroll
    for (int rt = 0; rt < 4; ++rt) {
        acc[rt] = __builtin_amdgcn_mfma_f32_16x16x32_bf16(wf[rt * 2 + 0], bx0, z4, 0, 0, 0);
        acc[rt] = __builtin_amdgcn_mfma_f32_16x16x32_bf16(wf[rt * 2 + 1], bx1, acc[rt], 0, 0, 0);
    }
    if (fr) {   // Y1^T writeback (same-wave in-order LDS)
        #pragma unroll
        for (int rt = 0; rt < 4; ++rt) {
            const int n0 = rt * 16 + g * 4;          // D row = (lane>>4)*4 + reg (+16rt)
            const unsigned int d0 = (unsigned short)f2bf(acc[rt][0]) |
                                    ((unsigned int)(unsigned short)f2bf(acc[rt][1]) << 16);
            const unsigned int d1 = (unsigned short)f2bf(acc[rt][2]) |
                                    ((unsigned int)(unsigned short)f2bf(acc[rt][3]) << 16);
            if (n0 + 1 < NNODE) *(unsigned int*)&XT[w][f16][n0] = d0;
            if (n0 + 3 < NNODE) *(unsigned int*)&XT[w][f16][n0 + 2] = d1;
        }
    }

    // hop 2: Y2 = Wn @ Y1 (same W frags from registers)
    {
        const short* p0 = fr ? &XT[w][f16][g * 8]      : zp;
        const short* p1 = fr ? &XT[w][f16][32 + g * 8] : zp;
        bx0 = *(const bf16x8*)p0;
        bx1 = *(const bf16x8*)p1;
    }
    #pragma unroll
    for (int rt = 0; rt < 4; ++rt) {
        acc[rt] = __builtin_amdgcn_mfma_f32_16x16x32_bf16(wf[rt * 2 + 0], bx0, z4, 0, 0, 0);
        acc[rt] = __builtin_amdgcn_mfma_f32_16x16x32_bf16(wf[rt * 2 + 1], bx1, acc[rt], 0, 0, 0);
    }
    // scatter Y2 with FULL Y2A coverage: lanes f16<8 write k=0..7
    // (features from acc, k=5 bias=1.0 for real rows, zeros elsewhere)
    if (f16 < 8) {
        #pragma unroll
        for (int rt = 0; rt < 4; ++rt) {
            const int n0 = rt * 16 + g * 4;
            #pragma unroll
            for (int r = 0; r < 4; ++r) {
                const int n = n0 + r;
                short val = 0;
                if (n < NNODE) {
                    val = (f16 < FIN) ? f2bf(acc[rt][r])
                                      : ((f16 == FIN) ? (short)0x3F80 : (short)0);
                }
                Y2A[w][n][f16] = val;
            }
        }
    }

    // ---- lin A-frags from Y2A (same-wave in-order LDS) ----
    bf16x8 af[4];
    #pragma unroll
    for (int rt = 0; rt < 4; ++rt) {
        const short* ap = (lane < 16) ? &Y2A[w][lane + 16 * rt][0] : zp;
        af[rt] = *(const bf16x8*)ap;
    }

    // ---- 25 col-tiles of MFMA; fused relu-pool + per-lane fc partials ----
    float o0 = 0.f, o1 = 0.f;
    for (int ct = 0; ct < 25; ++ct) {
        const short* bp = (lane < 16) ? &lwT[16 * ct + f16][0] : zp;
        const bf16x8 bfr = *(const bf16x8*)bp;
        const float2 fw = *(const float2*)&fcs[(16 * ct + f16) * 2];
        const f32x4 ac0 = __builtin_amdgcn_mfma_f32_16x16x32_bf16(af[0], bfr, z4, 0, 0, 0);
        const f32x4 ac1 = __builtin_amdgcn_mfma_f32_16x16x32_bf16(af[1], bfr, z4, 0, 0, 0);
        const f32x4 ac2 = __builtin_amdgcn_mfma_f32_16x16x32_bf16(af[2], bfr, z4, 0, 0, 0);
        const f32x4 ac3 = __builtin_amdgcn_mfma_f32_16x16x32_bf16(af[3], bfr, z4, 0, 0, 0);
        float p0 = fmaxf(ac0[0],0.f)+fmaxf(ac0[1],0.f)+fmaxf(ac0[2],0.f)+fmaxf(ac0[3],0.f);
        float p1 = fmaxf(ac1[0],0.f)+fmaxf(ac1[1],0.f)+fmaxf(ac1[2],0.f)+fmaxf(ac1[3],0.f);
        float p2 = fmaxf(ac2[0],0.f)+fmaxf(ac2[1],0.f)+fmaxf(ac2[2],0.f)+fmaxf(ac2[3],0.f);
        float p3 = fmaxf(ac3[0],0.f)+fmaxf(ac3[1],0.f)+fmaxf(ac3[2],0.f)+fmaxf(ac3[3],0.f);
        const float pc = (p0 + p1) + (p2 + p3);     // 16 rows of col 16ct+f16
        o0 = fmaf(pc, fw.x, o0);
        o1 = fmaf(pc, fw.y, o1);
    }
    // one full-wave butterfly over (row-group, col) partials
    #pragma unroll
    for (int s = 32; s > 0; s >>= 1) {
        o0 += __shfl_xor(o0, s, 64);
        o1 += __shfl_xor(o1, s, 64);
    }
    if (lane == 0) {
        out[2 * b + 0] = o0 + fc_b[0];
        out[2 * b + 1] = o1 + fc_b[1];
    }
}

extern "C" void kernel_launch(void* const* d_in, const int* in_sizes, int n_in,
                              void* d_out, int out_size, void* d_ws, size_t ws_size,
                              hipStream_t stream) {
    const float* X     = (const float*)d_in[0];
    const float* ew    = (const float*)d_in[2];
    const float* lin_w = (const float*)d_in[3];
    const float* lin_b = (const float*)d_in[4];
    const float* fc_w  = (const float*)d_in[5];
    const float* fc_b  = (const float*)d_in[6];
    const int*   tx    = (const int*)d_in[9];
    const int*   ty    = (const int*)d_in[10];

    float* outp = (float*)d_out;
    const int B = in_sizes[0] / (NNODE * FIN);   // 4096

    rgnn_fused<<<(B + WAVES - 1) / WAVES, 1024, 0, stream>>>(
        X, ew, tx, ty, lin_w, lin_b, fc_w, fc_b, outp, B);
}

// Round 8
// 19.483 us; speedup vs baseline: 5.3580x; 1.0718x over previous
//
#include <hip/hip_runtime.h>
#include <hip/hip_bf16.h>

#define NNODE 62
#define FIN 5
#define HID 400
#define HIDP 416        // 13 tiles of 32 cols (pad cols zero)
#define NTRIL 1953
#define MST 63          // f32 Wn row stride
#define WST 72          // XT row stride in shorts (144B)
#define WAVES 16        // 1024-thread block, 1 graph per wave, 1 block per CU

typedef __attribute__((ext_vector_type(8)))  short bf16x8;
typedef __attribute__((ext_vector_type(4)))  float f32x4;
typedef __attribute__((ext_vector_type(8)))  float f32x8;
typedef __attribute__((ext_vector_type(2)))  float f32x2;
typedef __attribute__((ext_vector_type(16))) float f32x16;

static __device__ __forceinline__ short f2bf(float x) {
    __hip_bfloat16 h = __float2bfloat16(x);
    return *reinterpret_cast<short*>(&h);
}

// relu + horizontal sum of a 32x32 MFMA accumulator (16 f32/lane).
// Vector ops give the compiler a shot at v_pk_max_f32 / v_pk_add_f32.
static __device__ __forceinline__ float hsum16_relu(f32x16 d) {
    const f32x16 z = {};
    const f32x16 r = __builtin_elementwise_max(d, z);
    const f32x8 a = __builtin_shufflevector(r, r, 0,1,2,3,4,5,6,7)
                  + __builtin_shufflevector(r, r, 8,9,10,11,12,13,14,15);
    const f32x4 b = __builtin_shufflevector(a, a, 0,1,2,3)
                  + __builtin_shufflevector(a, a, 4,5,6,7);
    const f32x2 c = __builtin_shufflevector(b, b, 0,1)
                  + __builtin_shufflevector(b, b, 2,3);
    return c[0] + c[1];
}

// One dispatch: 256 blocks x 1024 threads (16 waves) = 1 block/CU, 4 waves/SIMD.
// Block builds Wn/Wfrag/lwT once; each wave computes one graph:
//   hops (16x16x32 MFMA, W-frags in VGPRs) -> lin (32x32x16 MFMA, 13 tiles,
//   prefetched B-frags) -> fused relu-pool + fc, one butterfly.
__global__ __launch_bounds__(1024, 4) void rgnn_fused(
        const float* __restrict__ X,     const float* __restrict__ ew,
        const int* __restrict__ tx,      const int* __restrict__ ty,
        const float* __restrict__ lin_w, const float* __restrict__ lin_b,
        const float* __restrict__ fc_w,  const float* __restrict__ fc_b,
        float* __restrict__ out, int B) {
    __shared__ float Wn[NNODE * MST];                   // 15624 B
    __shared__ float dinv[64];
    __shared__ __align__(16) short Wfrag[8][64][8];     // 8192 B: 16x16 A-frag order
    __shared__ __align__(16) short lwT[HIDP][8];        // 6656 B: [col][k], k=5 = bias, pad cols 0
    __shared__ float fcs[HIDP * 2];                     // 3328 B (pad cols 0)
    __shared__ __align__(16) short XT[WAVES][FIN][WST]; // 11520 B: X^T then Y1^T
    __shared__ __align__(16) short Y2A[WAVES][64][8];   // 16384 B: lin A rows
    __shared__ __align__(16) short Zs[8];               // ~62 KB total

    const int t = threadIdx.x;
    const int w = t >> 6;
    const int lane = t & 63;
    const int b = blockIdx.x * WAVES + w;

    // ---- phase 0: stage weights, scatter W, load X ----
    for (int i = t; i < HIDP * 8; i += 1024) {
        const int c = i >> 3, k = i & 7;
        float v = 0.f;
        if (c < HID) {
            if (k < FIN) v = lin_w[k * HID + c];
            else if (k == FIN) v = lin_b[c];
        }
        lwT[c][k] = f2bf(v);
    }
    for (int i = t; i < HIDP * 2; i += 1024) fcs[i] = (i < HID * 2) ? fc_w[i] : 0.f;
    if (t < 8) Zs[t] = 0;
    for (int e = t; e < NTRIL; e += 1024) {
        const int x = tx[e], y = ty[e];
        const float v = ew[e];
        Wn[x * MST + y] = v;
        Wn[y * MST + x] = v;
    }
    if (b < B) {
        const float* xb = X + (size_t)b * (NNODE * FIN);
        for (int idx = lane; idx < NNODE * FIN; idx += 64) {
            const int n = idx / FIN, f = idx - n * FIN;
            XT[w][f][n] = f2bf(xb[idx]);
        }
        if (lane < FIN) *(unsigned int*)&XT[w][lane][62] = 0u;   // node pads 62,63
    }
    __syncthreads();

    // ---- phase 1: row degrees -> D^-1/2 (16 threads per row) ----
    if (t < NNODE * 16) {
        const int r = t >> 4, j = t & 15;
        float s = 0.f;
        for (int k = j; k < NNODE; k += 16) s += fabsf(Wn[r * MST + k]);
        s += __shfl_xor(s, 8);
        s += __shfl_xor(s, 4);
        s += __shfl_xor(s, 2);
        s += __shfl_xor(s, 1);
        if (j == 0) dinv[r] = (s > 0.f) ? (1.0f / sqrtf(s)) : 0.f;
    }
    __syncthreads();

    // ---- phase 2: normalize + convert into 16x16 A-frag order (threads 0-511) ----
    if (t < 512) {
        const int fi = t >> 6, l = t & 63;           // fi = rt*2 + ks
        const int rt = fi >> 1, ks = fi & 1;
        const int row = (l & 15) + 16 * rt;
        const int k0 = ks * 32 + (l >> 4) * 8;
        union { short s[8]; bf16x8 v8; } u;
        #pragma unroll
        for (int j = 0; j < 8; ++j) {
            const int k = k0 + j;
            u.s[j] = (row < NNODE && k < NNODE)
                   ? f2bf(Wn[row * MST + k] * dinv[row] * dinv[k]) : (short)0;
        }
        *(bf16x8*)&Wfrag[fi][l][0] = u.v8;
    }
    __syncthreads();    // last block-wide barrier

    if (b >= B) return;

    // ---- per-wave: cache W A-frags in VGPRs ----
    bf16x8 wf[8];
    #pragma unroll
    for (int fi = 0; fi < 8; ++fi) wf[fi] = *(const bf16x8*)&Wfrag[fi][lane][0];

    const int f16 = lane & 15;
    const int g   = lane >> 4;
    const bool fr = (f16 < FIN);
    const short* zp = &Zs[0];
    const f32x4 z4 = {0.f, 0.f, 0.f, 0.f};

    // hop 1: Y1 = Wn @ X  (16x16x32)
    bf16x8 bx0, bx1;
    {
        const short* p0 = fr ? &XT[w][f16][g * 8]      : zp;
        const short* p1 = fr ? &XT[w][f16][32 + g * 8] : zp;
        bx0 = *(const bf16x8*)p0;
        bx1 = *(const bf16x8*)p1;
    }
    f32x4 acc[4];
    #pragma unroll
    for (int rt = 0; rt < 4; ++rt) {
        acc[rt] = __builtin_amdgcn_mfma_f32_16x16x32_bf16(wf[rt * 2 + 0], bx0, z4, 0, 0, 0);
        acc[rt] = __builtin_amdgcn_mfma_f32_16x16x32_bf16(wf[rt * 2 + 1], bx1, acc[rt], 0, 0, 0);
    }
    if (fr) {   // Y1^T writeback (same-wave in-order LDS)
        #pragma unroll
        for (int rt = 0; rt < 4; ++rt) {
            const int n0 = rt * 16 + g * 4;          // D row = (lane>>4)*4 + reg (+16rt)
            const unsigned int d0 = (unsigned short)f2bf(acc[rt][0]) |
                                    ((unsigned int)(unsigned short)f2bf(acc[rt][1]) << 16);
            const unsigned int d1 = (unsigned short)f2bf(acc[rt][2]) |
                                    ((unsigned int)(unsigned short)f2bf(acc[rt][3]) << 16);
            if (n0 + 1 < NNODE) *(unsigned int*)&XT[w][f16][n0] = d0;
            if (n0 + 3 < NNODE) *(unsigned int*)&XT[w][f16][n0 + 2] = d1;
        }
    }

    // hop 2: Y2 = Wn @ Y1
    {
        const short* p0 = fr ? &XT[w][f16][g * 8]      : zp;
        const short* p1 = fr ? &XT[w][f16][32 + g * 8] : zp;
        bx0 = *(const bf16x8*)p0;
        bx1 = *(const bf16x8*)p1;
    }
    #pragma unroll
    for (int rt = 0; rt < 4; ++rt) {
        acc[rt] = __builtin_amdgcn_mfma_f32_16x16x32_bf16(wf[rt * 2 + 0], bx0, z4, 0, 0, 0);
        acc[rt] = __builtin_amdgcn_mfma_f32_16x16x32_bf16(wf[rt * 2 + 1], bx1, acc[rt], 0, 0, 0);
    }
    // scatter Y2 with FULL Y2A coverage: lanes f16<8 write k=0..7
    if (f16 < 8) {
        #pragma unroll
        for (int rt = 0; rt < 4; ++rt) {
            const int n0 = rt * 16 + g * 4;
            #pragma unroll
            for (int r = 0; r < 4; ++r) {
                const int n = n0 + r;
                short val = 0;
                if (n < NNODE) {
                    val = (f16 < FIN) ? f2bf(acc[rt][r])
                                      : ((f16 == FIN) ? (short)0x3F80 : (short)0);
                }
                Y2A[w][n][f16] = val;
            }
        }
    }

    // ---- lin stage (32x32x16): A rows = Y2A nodes; lanes 0-31 carry k=0..7 ----
    const int r32 = lane & 31;
    const bool alo = (lane < 32);
    bf16x8 af0, af1;
    {
        const short* a0 = alo ? &Y2A[w][r32][0]      : zp;
        const short* a1 = alo ? &Y2A[w][32 + r32][0] : zp;
        af0 = *(const bf16x8*)a0;
        af1 = *(const bf16x8*)a1;
    }

    // 13 col-tiles, software-pipelined B-frag/fc prefetch
    const f32x16 z16 = {};
    float o0 = 0.f, o1 = 0.f;
    bf16x8 bfr;
    float2 fw;
    {
        const short* bp = alo ? &lwT[r32][0] : zp;
        bfr = *(const bf16x8*)bp;
        fw  = *(const float2*)&fcs[r32 * 2];
    }
    #pragma unroll
    for (int ct = 0; ct < 13; ++ct) {
        bf16x8 nb = bfr;
        float2 nf = fw;
        if (ct < 12) {
            const short* bp = alo ? &lwT[32 * (ct + 1) + r32][0] : zp;
            nb = *(const bf16x8*)bp;
            nf = *(const float2*)&fcs[(32 * (ct + 1) + r32) * 2];
        }
        const f32x16 d0 = __builtin_amdgcn_mfma_f32_32x32x16_bf16(af0, bfr, z16, 0, 0, 0);
        const f32x16 d1 = __builtin_amdgcn_mfma_f32_32x32x16_bf16(af1, bfr, z16, 0, 0, 0);
        const float pc = hsum16_relu(d0) + hsum16_relu(d1);   // rows of col r32
        o0 = fmaf(pc, fw.x, o0);
        o1 = fmaf(pc, fw.y, o1);
        bfr = nb;
        fw  = nf;
    }

    // one full-wave butterfly over (row-half, col) partials
    #pragma unroll
    for (int s = 32; s > 0; s >>= 1) {
        o0 += __shfl_xor(o0, s, 64);
        o1 += __shfl_xor(o1, s, 64);
    }
    if (lane == 0) {
        out[2 * b + 0] = o0 + fc_b[0];
        out[2 * b + 1] = o1 + fc_b[1];
    }
}

extern "C" void kernel_launch(void* const* d_in, const int* in_sizes, int n_in,
                              void* d_out, int out_size, void* d_ws, size_t ws_size,
                              hipStream_t stream) {
    const float* X     = (const float*)d_in[0];
    const float* ew    = (const float*)d_in[2];
    const float* lin_w = (const float*)d_in[3];
    const float* lin_b = (const float*)d_in[4];
    const float* fc_w  = (const float*)d_in[5];
    const float* fc_b  = (const float*)d_in[6];
    const int*   tx    = (const int*)d_in[9];
    const int*   ty    = (const int*)d_in[10];

    float* outp = (float*)d_out;
    const int B = in_sizes[0] / (NNODE * FIN);   // 4096

    rgnn_fused<<<(B + WAVES - 1) / WAVES, 1024, 0, stream>>>(
        X, ew, tx, ty, lin_w, lin_b, fc_w, fc_b, outp, B);
}

// Round 9
// 19.357 us; speedup vs baseline: 5.3929x; 1.0065x over previous
//
#include <hip/hip_runtime.h>
#include <hip/hip_bf16.h>

#define NNODE 62
#define FIN 5
#define HID 400
#define HIDP 416        // 13 tiles of 32 cols (pad cols zero)
#define NTRIL 1953
#define MST 63          // f32 Wn row stride
#define WST 72          // XT row stride in shorts (144B)
#define WAVES 16        // 1024-thread block, 1 graph per wave, 1 block per CU

typedef __attribute__((ext_vector_type(8)))  short bf16x8;
typedef __attribute__((ext_vector_type(4)))  float f32x4;
typedef __attribute__((ext_vector_type(8)))  float f32x8;
typedef __attribute__((ext_vector_type(2)))  float f32x2;
typedef __attribute__((ext_vector_type(16))) float f32x16;

static __device__ __forceinline__ short f2bf(float x) {
    __hip_bfloat16 h = __float2bfloat16(x);
    return *reinterpret_cast<short*>(&h);
}

// relu + horizontal sum of a 32x32 MFMA accumulator (16 f32/lane).
static __device__ __forceinline__ float hsum16_relu(f32x16 d) {
    const f32x16 z = {};
    const f32x16 r = __builtin_elementwise_max(d, z);
    const f32x8 a = __builtin_shufflevector(r, r, 0,1,2,3,4,5,6,7)
                  + __builtin_shufflevector(r, r, 8,9,10,11,12,13,14,15);
    const f32x4 b = __builtin_shufflevector(a, a, 0,1,2,3)
                  + __builtin_shufflevector(a, a, 4,5,6,7);
    const f32x2 c = __builtin_shufflevector(b, b, 0,1)
                  + __builtin_shufflevector(b, b, 2,3);
    return c[0] + c[1];
}

// 256 blocks x 1024 threads (16 waves) = 1 block/CU, 4 waves/SIMD.
// Block builds Wn/Wfrag/lwT once; each wave computes one graph:
//   hops (16x16x32, W-frags in VGPRs) -> lin (32x32x16, 13 tiles,
//   2-deep software pipeline) -> fused relu-pool + fc, one butterfly.
__global__ __launch_bounds__(1024, 4) void rgnn_fused(
        const float* __restrict__ X,     const float* __restrict__ ew,
        const int* __restrict__ tx,      const int* __restrict__ ty,
        const float* __restrict__ lin_w, const float* __restrict__ lin_b,
        const float* __restrict__ fc_w,  const float* __restrict__ fc_b,
        float* __restrict__ out, int B) {
    __shared__ float Wn[NNODE * MST];                   // 15624 B
    __shared__ float dinv[64];
    __shared__ __align__(16) short Wfrag[8][64][8];     // 8192 B: 16x16 A-frag order
    __shared__ __align__(16) short lwT[HIDP][8];        // 6656 B: [col][k], k=5 = bias
    __shared__ float fcs[HIDP * 2];                     // 3328 B
    __shared__ __align__(16) short XT[WAVES][FIN][WST]; // 11520 B: X^T then Y1^T
    __shared__ __align__(16) short Y2A[WAVES][64][8];   // 16384 B: lin A rows
    __shared__ __align__(16) short Zs[8];               // ~62 KB total

    const int t = threadIdx.x;
    const int w = t >> 6;
    const int lane = t & 63;
    const int b = blockIdx.x * WAVES + w;

    const int f16 = lane & 15;
    const int g   = lane >> 6 ? 0 : (lane >> 4);        // = lane>>4 (lane<64 always)
    const bool fr = (f16 < FIN);

    // ---- phase 0: stage weights, scatter W, load X ----
    for (int i = t; i < HIDP * 8; i += 1024) {
        const int c = i >> 3, k = i & 7;
        float v = 0.f;
        if (c < HID) {
            if (k < FIN) v = lin_w[k * HID + c];
            else if (k == FIN) v = lin_b[c];
        }
        lwT[c][k] = f2bf(v);
    }
    for (int i = t; i < HIDP * 2; i += 1024) fcs[i] = (i < HID * 2) ? fc_w[i] : 0.f;
    if (t < 8) Zs[t] = 0;
    for (int e = t; e < NTRIL; e += 1024) {
        const int x = tx[e], y = ty[e];
        const float v = ew[e];
        Wn[x * MST + y] = v;
        Wn[y * MST + x] = v;
    }
    bf16x8 bx0 = {}, bx1 = {};
    if (b < B) {
        const float* xb = X + (size_t)b * (NNODE * FIN);
        for (int idx = lane; idx < NNODE * FIN; idx += 64) {
            const int n = idx / FIN, f = idx - n * FIN;
            XT[w][f][n] = f2bf(xb[idx]);
        }
        if (lane < FIN) *(unsigned int*)&XT[w][lane][62] = 0u;   // node pads 62,63
        // EARLY hop-1 B-frag load: same-wave RAW on XT is in-order, no barrier
        // needed; masked lanes use a register zero (Zs not yet synced here).
        const int fc16 = fr ? f16 : 0;
        const bf16x8 e0 = *(const bf16x8*)&XT[w][fc16][g * 8];
        const bf16x8 e1 = *(const bf16x8*)&XT[w][fc16][32 + g * 8];
        if (fr) { bx0 = e0; bx1 = e1; }
    }
    __syncthreads();

    // ---- phase 1: row degrees -> D^-1/2 (16 threads per row) ----
    if (t < NNODE * 16) {
        const int r = t >> 4, j = t & 15;
        float s = 0.f;
        for (int k = j; k < NNODE; k += 16) s += fabsf(Wn[r * MST + k]);
        s += __shfl_xor(s, 8);
        s += __shfl_xor(s, 4);
        s += __shfl_xor(s, 2);
        s += __shfl_xor(s, 1);
        if (j == 0) dinv[r] = (s > 0.f) ? (1.0f / sqrtf(s)) : 0.f;
    }
    __syncthreads();

    // ---- phase 2: normalize + convert into 16x16 A-frag order (threads 0-511) ----
    if (t < 512) {
        const int fi = t >> 6, l = t & 63;           // fi = rt*2 + ks
        const int rt = fi >> 1, ks = fi & 1;
        const int row = (l & 15) + 16 * rt;
        const int k0 = ks * 32 + (l >> 4) * 8;
        union { short s[8]; bf16x8 v8; } u;
        #pragma unroll
        for (int j = 0; j < 8; ++j) {
            const int k = k0 + j;
            u.s[j] = (row < NNODE && k < NNODE)
                   ? f2bf(Wn[row * MST + k] * dinv[row] * dinv[k]) : (short)0;
        }
        *(bf16x8*)&Wfrag[fi][l][0] = u.v8;
    }
    __syncthreads();    // last block-wide barrier

    if (b >= B) return;

    // ---- per-wave: cache W A-frags in VGPRs ----
    bf16x8 wf[8];
    #pragma unroll
    for (int fi = 0; fi < 8; ++fi) wf[fi] = *(const bf16x8*)&Wfrag[fi][lane][0];

    const short* zp = &Zs[0];
    const f32x4 z4 = {0.f, 0.f, 0.f, 0.f};

    // hop 1: Y1 = Wn @ X  (bx0/bx1 loaded pre-barrier)
    f32x4 acc[4];
    __builtin_amdgcn_s_setprio(1);
    #pragma unroll
    for (int rt = 0; rt < 4; ++rt) {
        acc[rt] = __builtin_amdgcn_mfma_f32_16x16x32_bf16(wf[rt * 2 + 0], bx0, z4, 0, 0, 0);
        acc[rt] = __builtin_amdgcn_mfma_f32_16x16x32_bf16(wf[rt * 2 + 1], bx1, acc[rt], 0, 0, 0);
    }
    __builtin_amdgcn_s_setprio(0);
    if (fr) {   // Y1^T writeback (same-wave in-order LDS)
        #pragma unroll
        for (int rt = 0; rt < 4; ++rt) {
            const int n0 = rt * 16 + g * 4;          // D row = (lane>>4)*4 + reg (+16rt)
            const unsigned int d0 = (unsigned short)f2bf(acc[rt][0]) |
                                    ((unsigned int)(unsigned short)f2bf(acc[rt][1]) << 16);
            const unsigned int d1 = (unsigned short)f2bf(acc[rt][2]) |
                                    ((unsigned int)(unsigned short)f2bf(acc[rt][3]) << 16);
            if (n0 + 1 < NNODE) *(unsigned int*)&XT[w][f16][n0] = d0;
            if (n0 + 3 < NNODE) *(unsigned int*)&XT[w][f16][n0 + 2] = d1;
        }
    }

    // hop 2: Y2 = Wn @ Y1
    {
        const short* p0 = fr ? &XT[w][f16][g * 8]      : zp;
        const short* p1 = fr ? &XT[w][f16][32 + g * 8] : zp;
        bx0 = *(const bf16x8*)p0;
        bx1 = *(const bf16x8*)p1;
    }
    __builtin_amdgcn_s_setprio(1);
    #pragma unroll
    for (int rt = 0; rt < 4; ++rt) {
        acc[rt] = __builtin_amdgcn_mfma_f32_16x16x32_bf16(wf[rt * 2 + 0], bx0, z4, 0, 0, 0);
        acc[rt] = __builtin_amdgcn_mfma_f32_16x16x32_bf16(wf[rt * 2 + 1], bx1, acc[rt], 0, 0, 0);
    }
    __builtin_amdgcn_s_setprio(0);
    // scatter Y2 with FULL Y2A coverage: lanes f16<8 write k=0..7
    if (f16 < 8) {
        #pragma unroll
        for (int rt = 0; rt < 4; ++rt) {
            const int n0 = rt * 16 + g * 4;
            #pragma unroll
            for (int r = 0; r < 4; ++r) {
                const int n = n0 + r;
                short val = 0;
                if (n < NNODE) {
                    val = (f16 < FIN) ? f2bf(acc[rt][r])
                                      : ((f16 == FIN) ? (short)0x3F80 : (short)0);
                }
                Y2A[w][n][f16] = val;
            }
        }
    }

    // ---- lin stage (32x32x16): A rows = Y2A nodes; lanes 0-31 carry k=0..7 ----
    const int r32 = lane & 31;
    const bool alo = (lane < 32);
    bf16x8 af0, af1;
    {
        const short* a0 = alo ? &Y2A[w][r32][0]      : zp;
        const short* a1 = alo ? &Y2A[w][32 + r32][0] : zp;
        af0 = *(const bf16x8*)a0;
        af1 = *(const bf16x8*)a1;
    }

    // 13 col-tiles, 2-deep software pipeline: issue tile ct+1's MFMAs before
    // reducing tile ct (MFMA pipe fills while the VALU hsum chain drains).
    const f32x16 z16 = {};
    float o0 = 0.f, o1 = 0.f;
    bf16x8 bfr[2];
    float2 fw[2];
    f32x16 da[2], db[2];
    {
        const short* bp = alo ? &lwT[r32][0] : zp;
        bfr[0] = *(const bf16x8*)bp;
        fw[0]  = *(const float2*)&fcs[r32 * 2];
    }
    __builtin_amdgcn_s_setprio(1);
    da[0] = __builtin_amdgcn_mfma_f32_32x32x16_bf16(af0, bfr[0], z16, 0, 0, 0);
    db[0] = __builtin_amdgcn_mfma_f32_32x32x16_bf16(af1, bfr[0], z16, 0, 0, 0);
    __builtin_amdgcn_s_setprio(0);
    #pragma unroll
    for (int ct = 0; ct < 13; ++ct) {
        const int cur = ct & 1, nxt = cur ^ 1;
        if (ct < 12) {
            const short* bp = alo ? &lwT[32 * (ct + 1) + r32][0] : zp;
            bfr[nxt] = *(const bf16x8*)bp;
            fw[nxt]  = *(const float2*)&fcs[(32 * (ct + 1) + r32) * 2];
            __builtin_amdgcn_s_setprio(1);
            da[nxt] = __builtin_amdgcn_mfma_f32_32x32x16_bf16(af0, bfr[nxt], z16, 0, 0, 0);
            db[nxt] = __builtin_amdgcn_mfma_f32_32x32x16_bf16(af1, bfr[nxt], z16, 0, 0, 0);
            __builtin_amdgcn_s_setprio(0);
        }
        const float pc = hsum16_relu(da[cur]) + hsum16_relu(db[cur]);
        o0 = fmaf(pc, fw[cur].x, o0);
        o1 = fmaf(pc, fw[cur].y, o1);
    }

    // one full-wave butterfly over (row-half, col) partials
    #pragma unroll
    for (int s = 32; s > 0; s >>= 1) {
        o0 += __shfl_xor(o0, s, 64);
        o1 += __shfl_xor(o1, s, 64);
    }
    if (lane == 0) {
        out[2 * b + 0] = o0 + fc_b[0];
        out[2 * b + 1] = o1 + fc_b[1];
    }
}

extern "C" void kernel_launch(void* const* d_in, const int* in_sizes, int n_in,
                              void* d_out, int out_size, void* d_ws, size_t ws_size,
                              hipStream_t stream) {
    const float* X     = (const float*)d_in[0];
    const float* ew    = (const float*)d_in[2];
    const float* lin_w = (const float*)d_in[3];
    const float* lin_b = (const float*)d_in[4];
    const float* fc_w  = (const float*)d_in[5];
    const float* fc_b  = (const float*)d_in[6];
    const int*   tx    = (const int*)d_in[9];
    const int*   ty    = (const int*)d_in[10];

    float* outp = (float*)d_out;
    const int B = in_sizes[0] / (NNODE * FIN);   // 4096

    rgnn_fused<<<(B + WAVES - 1) / WAVES, 1024, 0, stream>>>(
        X, ew, tx, ty, lin_w, lin_b, fc_w, fc_b, outp, B);
}